// Round 7
// baseline (69.271 us; speedup 1.0000x reference)
//
#include <hip/hip_runtime.h>
#include <utility>

#define BATCH 32768
#define NPHI 35
#define SWEEPS 6

// ---------- compile-time combinatorics ----------
constexpr int choose2(int n){ return (n*(n-1))/2; }

constexpr int tri_id_sorted(int a,int b,int c){
  int id=0;
  for(int x=0;x<a;++x) id += choose2(6-x);
  for(int y=a+1;y<b;++y) id += (6-y);
  id += (c-b-1);
  return id;
}

constexpr int tri_id3(int a,int b,int c){
  int x=a,y=b,z=c;
  if (x>y){int t=x;x=y;y=t;}
  if (y>z){int t=y;y=z;z=t;}
  if (x>y){int t=x;x=y;y=t;}
  return tri_id_sorted(x,y,z);
}

constexpr int sgn3(int a,int b,int c){
  int inv = (a>b)+(a>c)+(b>c);
  return (inv&1)? -1 : 1;
}

constexpr int UT(int i,int j){
  return i*7 - (i*(i-1))/2 + (j-i);
}

constexpr int pair_k(int g){
  int idx=0;
  for(int k=0;k<7;++k) for(int l=k+1;l<7;++l){ if(idx==g) return k; ++idx; }
  return 0;
}
constexpr int pair_l(int g){
  int idx=0;
  for(int k=0;k<7;++k) for(int l=k+1;l<7;++l){ if(idx==g) return l; ++idx; }
  return 0;
}

// round-robin tournament: round r (0..6), slot s (0..2) -> disjoint pair
constexpr int rr_p(int r,int s){ int a=(r+1+s)%7, b=(r+6-s)%7; return a<b?a:b; }
constexpr int rr_q(int r,int s){ int a=(r+1+s)%7, b=(r+6-s)%7; return a<b?b:a; }

// ---------- per-(k,l)-group straight-line polynomial program ----------
struct GProg {
  int nt, nb;
  signed char t_dst[50], t_a[50], t_b[50], t_s[50]; unsigned char t_init[50];
  signed char b_dst[26], b_a[26], b_b[26], b_s[26];
};

constexpr GProg build_group(int k,int l){
  GProg P{}; P.nt=0; P.nb=0;
  bool tinit[7]={};
  for(int m=0;m<7;++m) for(int n2=m+1;n2<7;++n2){
    if(m==k||m==l||n2==k||n2==l) continue;
    int comp[3]={0,0,0}; int cn=0;
    for(int x=0;x<7;++x) if(x!=k&&x!=l&&x!=m&&x!=n2){ comp[cn]=x; ++cn; }
    int perm[7]={k,l,m,n2,comp[0],comp[1],comp[2]};
    int invc=0;
    for(int i=0;i<7;++i) for(int j=i+1;j<7;++j) if(perm[i]>perm[j]) ++invc;
    const int es=(invc&1)? -1 : 1;
    const int tcomp=tri_id_sorted(comp[0],comp[1],comp[2]);
    for(int j=0;j<7;++j){
      if(j==m||j==n2) continue;
      P.t_dst[P.nt]=(signed char)j;
      P.t_a [P.nt]=(signed char)tcomp;
      P.t_b [P.nt]=(signed char)tri_id3(j,m,n2);
      P.t_s [P.nt]=(signed char)(es*sgn3(j,m,n2));
      P.t_init[P.nt]=tinit[j]?0:1; tinit[j]=true;
      ++P.nt;
    }
  }
  for(int i=0;i<7;++i){
    if(i==k||i==l) continue;
    for(int j=i;j<7;++j){
      P.b_dst[P.nb]=(signed char)UT(i,j);
      P.b_a [P.nb]=(signed char)tri_id3(i,k,l);
      P.b_b [P.nb]=(signed char)j;
      P.b_s [P.nb]=(signed char)sgn3(i,k,l);
      ++P.nb;
    }
  }
  return P;
}

template<int G> inline constexpr GProg GP = build_group(pair_k(G), pair_l(G));

// ---------- constant-index execution (poly) ----------
template<int G,int Q>
__device__ __forceinline__ void t_step(float (&T)[7], const float (&ph)[NPHI]){
  constexpr int d=GP<G>.t_dst[Q], a=GP<G>.t_a[Q], b=GP<G>.t_b[Q];
  constexpr bool neg=(GP<G>.t_s[Q]<0), ini=(GP<G>.t_init[Q]!=0);
  const float x = neg ? -ph[a] : ph[a];
  if constexpr (ini) T[d] = x*ph[b];
  else               T[d] = fmaf(x, ph[b], T[d]);
}

template<int G,int Q>
__device__ __forceinline__ void b_step(float (&U)[28], const float (&T)[7],
                                       const float (&ph)[NPHI]){
  constexpr int d=GP<G>.b_dst[Q], a=GP<G>.b_a[Q], b=GP<G>.b_b[Q];
  constexpr bool neg=(GP<G>.b_s[Q]<0);
  const float x = neg ? -ph[a] : ph[a];
  U[d] = fmaf(x, T[b], U[d]);
}

template<int G,int... TQ>
__device__ __forceinline__ void run_t(float (&T)[7], const float (&ph)[NPHI],
                                      std::integer_sequence<int,TQ...>){
  (t_step<G,TQ>(T,ph), ...);
}
template<int G,int... BQ>
__device__ __forceinline__ void run_b(float (&U)[28], const float (&T)[7],
                                      const float (&ph)[NPHI],
                                      std::integer_sequence<int,BQ...>){
  (b_step<G,BQ>(U,T,ph), ...);
}

template<int G>
__device__ __forceinline__ void do_group(float (&U)[28], const float (&ph)[NPHI]){
  float T[7];
  run_t<G>(T, ph, std::make_integer_sequence<int, GP<G>.nt>{});
  run_b<G>(U, T, ph, std::make_integer_sequence<int, GP<G>.nb>{});
  __builtin_amdgcn_sched_barrier(0);
}

template<int G0,int... I>
__device__ __forceinline__ void groups_range_impl(float (&U)[28], const float (&ph)[NPHI],
                                                  std::integer_sequence<int,I...>){
  (do_group<G0+I>(U,ph), ...);
}
template<int G0,int G1>
__device__ __forceinline__ void groups_range(float (&U)[28], const float (&ph)[NPHI]){
  groups_range_impl<G0>(U, ph, std::make_integer_sequence<int, G1-G0>{});
}

// ---------- K1: poly, 4 waves/block, wave-sliced groups ----------
__global__ __launch_bounds__(256,1)
void PositivityConstraint_poly_kernel(const float* __restrict__ phi,
                                      float* __restrict__ bws){
  const int t    = threadIdx.x;
  const int wv   = t >> 6;        // 0..3  (slice id, wave-uniform)
  const int lane = t & 63;        // element within block
  const int eblk = blockIdx.x * 64;

  __shared__ float lph[64*36];          // staged phi, padded rows
  __shared__ float part[4*64*29];       // per-wave partial U, padded rows

  const float* __restrict__ gbase = phi + (size_t)eblk * NPHI;
  for (int i = t; i < 64*NPHI; i += 256){
    lph[(i/NPHI)*36 + (i%NPHI)] = gbase[i];
  }
  __syncthreads();

  float ph[NPHI];
  #pragma unroll
  for (int i=0;i<NPHI;++i) ph[i] = lph[lane*36 + i];

  float U[28];
  #pragma unroll
  for (int i=0;i<28;++i) U[i]=0.f;

  // wave-uniform slice branch: each wave executes exactly one body
  if      (wv==0) groups_range<0,5>(U, ph);
  else if (wv==1) groups_range<5,10>(U, ph);
  else if (wv==2) groups_range<10,15>(U, ph);
  else            groups_range<15,21>(U, ph);

  #pragma unroll
  for (int i=0;i<28;++i) part[(wv*64 + lane)*29 + i] = U[i];
  __syncthreads();

  // reduce 4 partials; thread t -> element e=t>>2, chunk c=t&3 (7 values)
  const int e = t >> 2, c = t & 3;
  float* __restrict__ dst = bws + (size_t)blockIdx.x*1792 + e*28 + c*7;
  #pragma unroll
  for (int j=0;j<7;++j){
    const int i = c*7 + j;
    const float s = part[(0*64+e)*29 + i] + part[(1*64+e)*29 + i]
                  + part[(2*64+e)*29 + i] + part[(3*64+e)*29 + i];
    dst[j] = s;
  }
}

// ---------- parallel-ordered Jacobi pieces ----------
template<int P,int Q>
__device__ __forceinline__ void jangle(const float (&A)[28],
                                       float &t, float &c, float &s){
  const float apq = A[UT(P,Q)];
  const float app = A[UT(P,P)];
  const float aqq = A[UT(Q,Q)];
  const float s2  = apq + apq;
  const float h   = aqq - app;
  const float r   = __builtin_amdgcn_sqrtf(fmaf(s2, s2, h*h));
  const float den = h + __builtin_copysignf(r + 1e-38f, h);
  t = s2 * __builtin_amdgcn_rcpf(den);
  c = __builtin_amdgcn_rsqf(fmaf(t, t, 1.0f));
  s = t*c;
}

template<int P,int Q>
__device__ __forceinline__ void japply(float (&A)[28], float t, float c, float s){
  const float apq = A[UT(P,Q)];
  A[UT(P,P)] = fmaf(-t, apq, A[UT(P,P)]);
  A[UT(Q,Q)] = fmaf( t, apq, A[UT(Q,Q)]);
  A[UT(P,Q)] = 0.0f;
  #pragma unroll
  for (int r2=0;r2<7;++r2){
    if (r2==P || r2==Q) continue;
    const int irp = (r2<P)? UT(r2,P) : UT(P,r2);
    const int irq = (r2<Q)? UT(r2,Q) : UT(Q,r2);
    const float arp = A[irp], arq = A[irq];
    A[irp] = fmaf(c, arp, -(s*arq));
    A[irq] = fmaf(c, arq,  (s*arp));
  }
}

template<int R>
__device__ __forceinline__ void jround(float (&A)[28]){
  constexpr int p0=rr_p(R,0), q0=rr_q(R,0);
  constexpr int p1=rr_p(R,1), q1=rr_q(R,1);
  constexpr int p2=rr_p(R,2), q2=rr_q(R,2);
  float t0,c0,s0, t1,c1,s1, t2,c2,s2;
  jangle<p0,q0>(A, t0,c0,s0);
  jangle<p1,q1>(A, t1,c1,s1);
  jangle<p2,q2>(A, t2,c2,s2);
  japply<p0,q0>(A, t0,c0,s0);
  japply<p1,q1>(A, t1,c1,s1);
  japply<p2,q2>(A, t2,c2,s2);
}

template<int... R>
__device__ __forceinline__ void jsweep(float (&A)[28],
                                       std::integer_sequence<int,R...>){
  (jround<R>(A), ...);
}

__device__ __forceinline__ float finish(const float (&A)[28]){
  float det = 1.0f;
  #pragma unroll
  for (int i=0;i<7;++i) det *= A[UT(i,i)];
  const float ad = fabsf(det) + 1e-12f;
  const float scale = __builtin_amdgcn_exp2f(__builtin_amdgcn_logf(ad) * (1.0f/9.0f));
  const float inv = __builtin_amdgcn_rcpf(scale);
  float sum = 0.0f;
  #pragma unroll
  for (int i=0;i<7;++i){
    const float ev = A[UT(i,i)]*inv;
    sum += fmaxf(1e-6f - ev, 0.0f);
  }
  return sum;
}

// ---------- K2: Jacobi, 1 element/thread ----------
__global__ __launch_bounds__(64,1)
void PositivityConstraint_89086211654295_kernel(const float* __restrict__ bws,
                                                float* __restrict__ out){
  const int gid = blockIdx.x*64 + threadIdx.x;

  const float4* __restrict__ src =
      reinterpret_cast<const float4*>(bws + (size_t)gid * 28);
  float A[28];
  #pragma unroll
  for (int k=0;k<7;++k){
    const float4 v = src[k];
    A[4*k+0] = v.x*(1.0f/6.0f);
    A[4*k+1] = v.y*(1.0f/6.0f);
    A[4*k+2] = v.z*(1.0f/6.0f);
    A[4*k+3] = v.w*(1.0f/6.0f);
  }

  for (int sweep=0; sweep<SWEEPS; ++sweep){
    jsweep(A, std::make_integer_sequence<int,7>{});
  }

  out[gid] = finish(A);
}

// ---------- launch ----------
extern "C" void kernel_launch(void* const* d_in, const int* in_sizes, int n_in,
                              void* d_out, int out_size, void* d_ws, size_t ws_size,
                              hipStream_t stream) {
  const float* phi = (const float*)d_in[0];
  float* out = (float*)d_out;
  float* bws = (float*)d_ws;                 // 32768*28*4 = 3.67 MB scratch
  (void)in_sizes; (void)n_in; (void)out_size; (void)ws_size;

  hipLaunchKernelGGL(PositivityConstraint_poly_kernel,
                     dim3(BATCH/64), dim3(256), 0, stream, phi, bws);
  hipLaunchKernelGGL(PositivityConstraint_89086211654295_kernel,
                     dim3(BATCH/64), dim3(64), 0, stream, bws, out);
}